// Round 3
// baseline (788.271 us; speedup 1.0000x reference)
//
#include <hip/hip_runtime.h>

#define XS 264           // X LDS row stride in bf16 elems (528 B; 2-way bank alias = free)
#define CHUNK_ELEMS 8192 // one 32k x 256n weight chunk, layout [quad][n][8]

typedef __bf16 bf16x8 __attribute__((ext_vector_type(8)));
typedef float f32x4 __attribute__((ext_vector_type(4)));

__device__ __forceinline__ unsigned short f2bf(float f) {
    unsigned int u = __float_as_uint(f);
    u += 0x7fffu + ((u >> 16) & 1u);
    return (unsigned short)(u >> 16);
}

// Workspace layout (bf16 element offsets). Layers 0..3 stored as swizzled chunk
// images: chunk c covers k in [c*32,c*32+32); element (quad,n,j) at offset
// ((quad*256+n)*8+j) holds W[n][c*32+quad*8+j].
#define OFF0 0        // L0: 5 chunks (K padded 132->160, cols permuted [f1|f2|rel,cell|0])
#define OFF1 40960    // L1: 8 chunks
#define OFF2 106496   // L2
#define OFF3 172032   // L3
#define OFF4 237568   // w4p: 16 x 256 plain (rows 3..15 zero)
#define WTOT 241664
#define NHWC_ELEMS (4 * 4096 * 64)

__global__ void prep_weights(const float* __restrict__ w0, const float* __restrict__ w1,
                             const float* __restrict__ w2, const float* __restrict__ w3,
                             const float* __restrict__ w4, unsigned short* __restrict__ wsp) {
    int idx = blockIdx.x * 256 + threadIdx.x;
    if (idx >= WTOT) return;
    unsigned short v = 0;
    if (idx < OFF4) {
        int l, base;
        if (idx < OFF1)      { l = 0; base = OFF0; }
        else if (idx < OFF2) { l = 1; base = OFF1; }
        else if (idx < OFF3) { l = 2; base = OFF2; }
        else                 { l = 3; base = OFF3; }
        int j = idx - base;
        int c = j >> 13;
        int u = j & 8191;
        int flat16 = u >> 3, jj = u & 7;
        int quad = flat16 >> 8, n = flat16 & 255;
        int k = c * 32 + quad * 8 + jj;
        if (l == 0) {
            if (k < 64)       v = f2bf(w0[n * 132 + k]);
            else if (k < 128) v = f2bf(w0[n * 132 + 68 + (k - 64)]);
            else if (k < 132) v = f2bf(w0[n * 132 + 64 + (k - 128)]);
        } else {
            const float* w = (l == 1) ? w1 : (l == 2) ? w2 : w3;
            v = f2bf(w[n * 256 + k]);
        }
    } else {
        int j = idx - OFF4;
        if ((j >> 8) < 3) v = f2bf(w4[j]);
    }
    wsp[idx] = v;
}

__global__ void transpose_nhwc(const float* __restrict__ inp1, const float* __restrict__ inp2,
                               unsigned short* __restrict__ t1, unsigned short* __restrict__ t2) {
    int idx = blockIdx.x * 256 + threadIdx.x;
    int tensor = idx >> 14;
    int pos = idx & 16383;
    const float* src = tensor ? inp2 : inp1;
    unsigned short* dst = tensor ? t2 : t1;
    int b = pos >> 12, flat = pos & 4095;
    const float* s = src + (size_t)b * 64 * 4096 + flat;
    unsigned short* d = dst + (size_t)pos * 64;
#pragma unroll
    for (int c = 0; c < 64; ++c) d[c] = f2bf(s[c * 4096]);
}

// wave wv stages its 4 KB slice of a 16 KB chunk via direct global->LDS DMA
__device__ __forceinline__ void stage_chunk(const unsigned short* __restrict__ g,
                                            unsigned short* l, int wv, int lane) {
#pragma unroll
    for (int j = 0; j < 4; ++j) {
        int jg = wv * 4 + j;
        const unsigned short* gp = g + ((size_t)jg * 64 + lane) * 8;  // 16 B per lane
        unsigned short* lp = l + (size_t)jg * 64 * 8;                 // wave-uniform base
        __builtin_amdgcn_global_load_lds(
            (const __attribute__((address_space(1))) void*)gp,
            (__attribute__((address_space(3))) void*)lp, 16, 0, 0);
    }
}

#define CFENCE() __asm__ volatile("" ::: "memory")

__global__ __launch_bounds__(256, 1)
void liif_mlp(const unsigned short* __restrict__ t1, const unsigned short* __restrict__ t2,
              const float* __restrict__ coord, const float* __restrict__ cell,
              const float* __restrict__ b0, const float* __restrict__ b1,
              const float* __restrict__ b2, const float* __restrict__ b3,
              const float* __restrict__ b4,
              const unsigned short* __restrict__ wsp,
              float* __restrict__ out) {
    __shared__ unsigned short Xs[128 * XS];          // 67,584 B
    __shared__ unsigned short WkB[3 * CHUNK_ELEMS];  // 49,152 B
    __shared__ float areaS[128];

    const int t = threadIdx.x;
    const int lane = t & 63;
    const int wv = t >> 6;            // 0..3

    // ---------------- gather: X [128 rows x 160 cols], 2 threads per row ----------------
    {
        int lr = t >> 1, sub = t & 1;
        int rg = blockIdx.x * 128 + lr;
        int p = rg >> 2, e = rg & 3;
        int b = p >> 16;
        float c0r = coord[(size_t)p * 2 + 0];
        float c1r = coord[(size_t)p * 2 + 1];
        float vx = (e & 2) ? 1.0f : -1.0f;
        float vy = (e & 1) ? 1.0f : -1.0f;
        const float lo = -1.0f + 1e-6f, hi = 1.0f - 1e-6f;
        float c0 = fminf(fmaxf(c0r + vx * (1.0f / 64.0f) + 1e-6f, lo), hi);
        float c1 = fminf(fmaxf(c1r + vy * (1.0f / 64.0f) + 1e-6f, lo), hi);
        int ih = (int)rintf((c0 + 1.0f) * 32.0f - 0.5f);
        ih = min(63, max(0, ih));
        int iw = (int)rintf((c1 + 1.0f) * 32.0f - 0.5f);
        iw = min(63, max(0, iw));
        int flat = ih * 64 + iw;
        size_t pos = (size_t)b * 4096 + flat;
        const uint4* g1 = (const uint4*)(t1 + pos * 64 + sub * 32);   // 64 B each
        const uint4* g2 = (const uint4*)(t2 + pos * 64 + sub * 32);
        uint4 v0 = g1[0], v1 = g1[1], v2 = g1[2], v3 = g1[3];
        uint4 u0 = g2[0], u1 = g2[1], u2 = g2[2], u3 = g2[3];
        uint4* d1 = (uint4*)&Xs[lr * XS + sub * 32];
        uint4* d2 = (uint4*)&Xs[lr * XS + 64 + sub * 32];
        d1[0] = v0; d1[1] = v1; d1[2] = v2; d1[3] = v3;
        d2[0] = u0; d2[1] = u1; d2[2] = u2; d2[3] = u3;
        if (sub == 0) {
            float qc0 = -1.0f + (2.0f * ih + 1.0f) * (1.0f / 64.0f);
            float qc1 = -1.0f + (2.0f * iw + 1.0f) * (1.0f / 64.0f);
            float rel0 = (c0r - qc0) * 64.0f;
            float rel1 = (c1r - qc1) * 64.0f;
            Xs[lr * XS + 128] = f2bf(rel0);
            Xs[lr * XS + 129] = f2bf(rel1);
            Xs[lr * XS + 130] = f2bf(cell[(size_t)p * 2 + 0] * 64.0f);
            Xs[lr * XS + 131] = f2bf(cell[(size_t)p * 2 + 1] * 64.0f);
#pragma unroll
            for (int c = 132; c < 160; ++c) Xs[lr * XS + c] = 0;
            areaS[lr] = fabsf(rel0 * rel1) + 1e-9f;
        }
    }

    // prefetch chunk 0 of layer 0 (DMA doesn't touch Xs; overlaps with gather tail)
    stage_chunk(wsp + OFF0, WkB, wv, lane);
    __syncthreads();

    const int ln15 = lane & 15;
    const int quad = lane >> 4;
    const int cb = wv * 64;          // this wave's 64 output cols

    const unsigned short* wlbase[4] = {wsp + OFF0, wsp + OFF1, wsp + OFF2, wsp + OFF3};
    const float* bptr[4] = {b0, b1, b2, b3};
    int cc = 0;

#pragma unroll
    for (int l = 0; l < 4; ++l) {
        const int nk = (l == 0) ? 5 : 8;
        const unsigned short* wl = wlbase[l];
        f32x4 acc[8][4];
#pragma unroll
        for (int mt = 0; mt < 8; ++mt)
#pragma unroll
            for (int nt = 0; nt < 4; ++nt)
                acc[mt][nt] = (f32x4){0.f, 0.f, 0.f, 0.f};

        // bias prefetch: lane needs cols cb + nt*16 + quad*4 .. +3 (broadcast within row-group)
        f32x4 bias[4];
#pragma unroll
        for (int nt = 0; nt < 4; ++nt)
            bias[nt] = *(const f32x4*)(bptr[l] + cb + nt * 16 + quad * 4);

#pragma unroll
        for (int i = 0; i < nk; ++i) {
            if (!(l == 3 && i == nk - 1)) {
                const unsigned short* nb = (i + 1 < nk)
                    ? wl + (size_t)(i + 1) * CHUNK_ELEMS
                    : wlbase[l + 1];
                stage_chunk(nb, WkB + ((cc + 1) % 3) * CHUNK_ELEMS, wv, lane);
                CFENCE();
                __builtin_amdgcn_s_waitcnt(0x0F74);   // vmcnt <= 4: chunk cc landed
            } else {
                CFENCE();
                __builtin_amdgcn_s_waitcnt(0x0F70);   // vmcnt(0)
            }
            __builtin_amdgcn_s_barrier();
            CFENCE();

            const unsigned short* Wc = WkB + (cc % 3) * CHUNK_ELEMS;
            bf16x8 bfr[4], af[8];
#pragma unroll
            for (int nt = 0; nt < 4; ++nt)
                bfr[nt] = *(const bf16x8*)&Wc[((size_t)quad * 256 + cb + nt * 16 + ln15) * 8];
#pragma unroll
            for (int mt = 0; mt < 8; ++mt)
                af[mt] = *(const bf16x8*)&Xs[(mt * 16 + ln15) * XS + i * 32 + quad * 8];
            // swapped operands: D = W·X^T -> lane holds row m=ln15, cols n=quad*4+reg
#pragma unroll
            for (int mt = 0; mt < 8; ++mt)
#pragma unroll
                for (int nt = 0; nt < 4; ++nt)
                    acc[mt][nt] = __builtin_amdgcn_mfma_f32_16x16x32_bf16(
                        bfr[nt], af[mt], acc[mt][nt], 0, 0, 0);
            ++cc;
        }
        __syncthreads();             // all Xs A-frag reads for this layer done
#pragma unroll
        for (int mt = 0; mt < 8; ++mt) {
            int row = mt * 16 + ln15;
#pragma unroll
            for (int nt = 0; nt < 4; ++nt) {
                int col = cb + nt * 16 + quad * 4;
                ushort4 pv;
                pv.x = f2bf(fmaxf(acc[mt][nt][0] + bias[nt][0], 0.0f));
                pv.y = f2bf(fmaxf(acc[mt][nt][1] + bias[nt][1], 0.0f));
                pv.z = f2bf(fmaxf(acc[mt][nt][2] + bias[nt][2], 0.0f));
                pv.w = f2bf(fmaxf(acc[mt][nt][3] + bias[nt][3], 0.0f));
                *(ushort4*)&Xs[row * XS + col] = pv;   // 8 B vector write
            }
        }
        __syncthreads();             // activations visible to all waves
    }

    // ---------------- layer 4: [128 x 256] @ [256 x 16], wave wv owns rows wv*32..+31 ----------------
    {
        f32x4 acc4[2] = {(f32x4){0.f, 0.f, 0.f, 0.f}, (f32x4){0.f, 0.f, 0.f, 0.f}};
        const unsigned short* W4 = wsp + OFF4;
#pragma unroll
        for (int k0 = 0; k0 < 256; k0 += 32) {
            bf16x8 bb = *(const bf16x8*)(W4 + ln15 * 256 + k0 + quad * 8);
#pragma unroll
            for (int mt = 0; mt < 2; ++mt) {
                bf16x8 a = *(const bf16x8*)&Xs[(wv * 32 + mt * 16 + ln15) * XS + k0 + quad * 8];
                acc4[mt] = __builtin_amdgcn_mfma_f32_16x16x32_bf16(a, bb, acc4[mt], 0, 0, 0);
            }
        }
#pragma unroll
        for (int mt = 0; mt < 2; ++mt) {
            int plocal = wv * 8 + mt * 4 + quad;     // point within block (0..31), reg r = branch
            float a0 = areaS[plocal * 4 + 0];
            float a1 = areaS[plocal * 4 + 1];
            float a2 = areaS[plocal * 4 + 2];
            float a3 = areaS[plocal * 4 + 3];
            float tot = a0 + a1 + a2 + a3;
            float r = (acc4[mt][0] * a3 + acc4[mt][1] * a2 + acc4[mt][2] * a1 + acc4[mt][3] * a0) / tot;
            if (ln15 < 3) {
                size_t pg = (size_t)blockIdx.x * 32 + plocal;
                out[pg * 3 + ln15] = r + b4[ln15];
            }
        }
    }
}

extern "C" void kernel_launch(void* const* d_in, const int* in_sizes, int n_in,
                              void* d_out, int out_size, void* d_ws, size_t ws_size,
                              hipStream_t stream) {
    const float* inp1  = (const float*)d_in[0];
    const float* inp2  = (const float*)d_in[1];
    const float* coord = (const float*)d_in[2];
    const float* cell  = (const float*)d_in[3];
    const float* w0 = (const float*)d_in[4];
    const float* b0 = (const float*)d_in[5];
    const float* w1 = (const float*)d_in[6];
    const float* b1 = (const float*)d_in[7];
    const float* w2 = (const float*)d_in[8];
    const float* b2 = (const float*)d_in[9];
    const float* w3 = (const float*)d_in[10];
    const float* b3 = (const float*)d_in[11];
    const float* w4 = (const float*)d_in[12];
    const float* b4 = (const float*)d_in[13];
    float* out = (float*)d_out;

    unsigned short* wsp = (unsigned short*)d_ws;
    unsigned short* t1 = wsp + WTOT;
    unsigned short* t2 = t1 + NHWC_ELEMS;

    prep_weights<<<(WTOT + 255) / 256, 256, 0, stream>>>(w0, w1, w2, w3, w4, wsp);
    transpose_nhwc<<<32768 / 256, 256, 0, stream>>>(inp1, inp2, t1, t2);
    liif_mlp<<<8192, 256, 0, stream>>>(t1, t2, coord, cell,
                                       b0, b1, b2, b3, b4, wsp, out);
}

// Round 4
// 674.316 us; speedup vs baseline: 1.1690x; 1.1690x over previous
//
#include <hip/hip_runtime.h>

#define XS 264           // X LDS row stride in bf16 elems (528 B; A/B b128 reads at bank floor)
#define CHUNK_ELEMS 8192 // one 32k x 256n weight chunk, layout [quad][n][8]

typedef __bf16 bf16x8 __attribute__((ext_vector_type(8)));
typedef float f32x4 __attribute__((ext_vector_type(4)));

__device__ __forceinline__ unsigned short f2bf(float f) {
    unsigned int u = __float_as_uint(f);
    u += 0x7fffu + ((u >> 16) & 1u);
    return (unsigned short)(u >> 16);
}

// Workspace layout (bf16 element offsets). Layers 0..3 stored as swizzled chunk
// images: chunk c covers k in [c*32,c*32+32); element (quad,n,j) at offset
// ((quad*256+n)*8+j) holds W[n][c*32+quad*8+j].
#define OFF0 0        // L0: 5 chunks (K padded 132->160, cols permuted [f1|f2|rel,cell|0])
#define OFF1 40960    // L1: 8 chunks
#define OFF2 106496   // L2
#define OFF3 172032   // L3
#define OFF4 237568   // w4p: 16 x 256 plain (rows 3..15 zero)
#define WTOT 241664
#define NHWC_ELEMS (4 * 4096 * 64)

__global__ void prep_weights(const float* __restrict__ w0, const float* __restrict__ w1,
                             const float* __restrict__ w2, const float* __restrict__ w3,
                             const float* __restrict__ w4, unsigned short* __restrict__ wsp) {
    int idx = blockIdx.x * 256 + threadIdx.x;
    if (idx >= WTOT) return;
    unsigned short v = 0;
    if (idx < OFF4) {
        int l, base;
        if (idx < OFF1)      { l = 0; base = OFF0; }
        else if (idx < OFF2) { l = 1; base = OFF1; }
        else if (idx < OFF3) { l = 2; base = OFF2; }
        else                 { l = 3; base = OFF3; }
        int j = idx - base;
        int c = j >> 13;
        int u = j & 8191;
        int flat16 = u >> 3, jj = u & 7;
        int quad = flat16 >> 8, n = flat16 & 255;
        int k = c * 32 + quad * 8 + jj;
        if (l == 0) {
            if (k < 64)       v = f2bf(w0[n * 132 + k]);
            else if (k < 128) v = f2bf(w0[n * 132 + 68 + (k - 64)]);
            else if (k < 132) v = f2bf(w0[n * 132 + 64 + (k - 128)]);
        } else {
            const float* w = (l == 1) ? w1 : (l == 2) ? w2 : w3;
            v = f2bf(w[n * 256 + k]);
        }
    } else {
        int j = idx - OFF4;
        if ((j >> 8) < 3) v = f2bf(w4[j]);
    }
    wsp[idx] = v;
}

__global__ void transpose_nhwc(const float* __restrict__ inp1, const float* __restrict__ inp2,
                               unsigned short* __restrict__ t1, unsigned short* __restrict__ t2) {
    int idx = blockIdx.x * 256 + threadIdx.x;
    int tensor = idx >> 14;
    int pos = idx & 16383;
    const float* src = tensor ? inp2 : inp1;
    unsigned short* dst = tensor ? t2 : t1;
    int b = pos >> 12, flat = pos & 4095;
    const float* s = src + (size_t)b * 64 * 4096 + flat;
    unsigned short* d = dst + (size_t)pos * 64;
#pragma unroll
    for (int c = 0; c < 64; ++c) d[c] = f2bf(s[c * 4096]);
}

// global chunk index 0..28 -> weight chunk base (compile-time folded under unroll)
__device__ __forceinline__ const unsigned short* chunk_ptr(const unsigned short* wsp, int g) {
    if (g < 5)  return wsp + OFF0 + (size_t)g * CHUNK_ELEMS;
    if (g < 13) return wsp + OFF1 + (size_t)(g - 5) * CHUNK_ELEMS;
    if (g < 21) return wsp + OFF2 + (size_t)(g - 13) * CHUNK_ELEMS;
    return wsp + OFF3 + (size_t)(g - 21) * CHUNK_ELEMS;
}

// wave wv stages its 2 KB slice of a 16 KB chunk via direct global->LDS DMA (8 waves)
__device__ __forceinline__ void stage_chunk(const unsigned short* __restrict__ g,
                                            unsigned short* l, int wv, int lane) {
#pragma unroll
    for (int j = 0; j < 2; ++j) {
        int jg = wv * 2 + j;
        const unsigned short* gp = g + ((size_t)jg * 64 + lane) * 8;  // 16 B per lane
        unsigned short* lp = l + (size_t)jg * 64 * 8;                 // wave-uniform base
        __builtin_amdgcn_global_load_lds(
            (const __attribute__((address_space(1))) void*)gp,
            (__attribute__((address_space(3))) void*)lp, 16, 0, 0);
    }
}

#define CFENCE() __asm__ volatile("" ::: "memory")

__global__ __launch_bounds__(512, 2)
void liif_mlp(const unsigned short* __restrict__ t1, const unsigned short* __restrict__ t2,
              const float* __restrict__ coord, const float* __restrict__ cell,
              const float* __restrict__ b0, const float* __restrict__ b1,
              const float* __restrict__ b2, const float* __restrict__ b3,
              const float* __restrict__ b4,
              const unsigned short* __restrict__ wsp,
              float* __restrict__ out) {
    __shared__ unsigned short Xs[128 * XS];          // 67,584 B
    __shared__ unsigned short WkB[4 * CHUNK_ELEMS];  // 65,536 B (depth-2 pipeline)
    __shared__ float areaS[128];

    const int t = threadIdx.x;
    const int lane = t & 63;
    const int wv = t >> 6;            // 0..7

    // ---------------- gather: X [128 rows x 160 cols], 4 threads per row ----------------
    {
        int lr = t >> 2, sub = t & 3;
        int rg = blockIdx.x * 128 + lr;
        int p = rg >> 2, e = rg & 3;
        int b = p >> 16;
        float c0r = coord[(size_t)p * 2 + 0];
        float c1r = coord[(size_t)p * 2 + 1];
        float vx = (e & 2) ? 1.0f : -1.0f;
        float vy = (e & 1) ? 1.0f : -1.0f;
        const float lo = -1.0f + 1e-6f, hi = 1.0f - 1e-6f;
        float c0 = fminf(fmaxf(c0r + vx * (1.0f / 64.0f) + 1e-6f, lo), hi);
        float c1 = fminf(fmaxf(c1r + vy * (1.0f / 64.0f) + 1e-6f, lo), hi);
        int ih = (int)rintf((c0 + 1.0f) * 32.0f - 0.5f);
        ih = min(63, max(0, ih));
        int iw = (int)rintf((c1 + 1.0f) * 32.0f - 0.5f);
        iw = min(63, max(0, iw));
        int flat = ih * 64 + iw;
        size_t pos = (size_t)b * 4096 + flat;
        const uint4* g1 = (const uint4*)(t1 + pos * 64 + sub * 16);
        const uint4* g2 = (const uint4*)(t2 + pos * 64 + sub * 16);
        uint4 a0 = g1[0], a1 = g1[1];
        uint4 c0v = g2[0], c1v = g2[1];
        uint4* d1 = (uint4*)&Xs[lr * XS + sub * 16];
        uint4* d2 = (uint4*)&Xs[lr * XS + 64 + sub * 16];
        d1[0] = a0; d1[1] = a1;
        d2[0] = c0v; d2[1] = c1v;
        if (sub == 0) {
            float qc0 = -1.0f + (2.0f * ih + 1.0f) * (1.0f / 64.0f);
            float qc1 = -1.0f + (2.0f * iw + 1.0f) * (1.0f / 64.0f);
            float rel0 = (c0r - qc0) * 64.0f;
            float rel1 = (c1r - qc1) * 64.0f;
            Xs[lr * XS + 128] = f2bf(rel0);
            Xs[lr * XS + 129] = f2bf(rel1);
            Xs[lr * XS + 130] = f2bf(cell[(size_t)p * 2 + 0] * 64.0f);
            Xs[lr * XS + 131] = f2bf(cell[(size_t)p * 2 + 1] * 64.0f);
#pragma unroll
            for (int c = 132; c < 160; ++c) Xs[lr * XS + c] = 0;
            areaS[lr] = fabsf(rel0 * rel1) + 1e-9f;
        }
    }

    // prefetch chunks 0,1 (DMA doesn't touch Xs; overlaps gather tail)
    stage_chunk(chunk_ptr(wsp, 0), WkB, wv, lane);
    stage_chunk(chunk_ptr(wsp, 1), WkB + CHUNK_ELEMS, wv, lane);
    __syncthreads();

    const int ln15 = lane & 15;
    const int quad = lane >> 4;
    const int mw = wv >> 2;          // row half: rows mw*64 .. +63
    const int nw = wv & 3;           // col group: cols nw*64 .. +63
    const int cb = nw * 64;
    const int rbase = mw * 64;

    const float* bptr[4] = {b0, b1, b2, b3};
    const int G0[4] = {0, 5, 13, 21};

#pragma unroll
    for (int l = 0; l < 4; ++l) {
        const int nk = (l == 0) ? 5 : 8;
        f32x4 acc[4][4];
#pragma unroll
        for (int mt = 0; mt < 4; ++mt)
#pragma unroll
            for (int nt = 0; nt < 4; ++nt)
                acc[mt][nt] = (f32x4){0.f, 0.f, 0.f, 0.f};

        // bias: lane covers cols cb + nt*16 + quad*4 .. +3
        f32x4 bias[4];
#pragma unroll
        for (int nt = 0; nt < 4; ++nt)
            bias[nt] = *(const f32x4*)(bptr[l] + cb + nt * 16 + quad * 4);

#pragma unroll
        for (int i = 0; i < nk; ++i) {
            const int g = G0[l] + i;          // compile-time under unroll
            if (g + 2 <= 28)
                stage_chunk(chunk_ptr(wsp, g + 2), WkB + ((g + 2) & 3) * CHUNK_ELEMS, wv, lane);
            CFENCE();
            const int rem = 28 - g;
            if (rem >= 2)      __builtin_amdgcn_s_waitcnt(0x0F74);  // vmcnt<=4: chunk g landed
            else if (rem == 1) __builtin_amdgcn_s_waitcnt(0x0F72);  // vmcnt<=2
            else               __builtin_amdgcn_s_waitcnt(0x0F70);  // vmcnt(0)
            __builtin_amdgcn_s_barrier();
            CFENCE();

            const unsigned short* Wc = WkB + (g & 3) * CHUNK_ELEMS;
            bf16x8 bfr[4], af[4];
#pragma unroll
            for (int nt = 0; nt < 4; ++nt)
                bfr[nt] = *(const bf16x8*)&Wc[((size_t)quad * 256 + cb + nt * 16 + ln15) * 8];
#pragma unroll
            for (int mt = 0; mt < 4; ++mt)
                af[mt] = *(const bf16x8*)&Xs[(rbase + mt * 16 + ln15) * XS + i * 32 + quad * 8];
            // swapped operands: D = W·X^T -> lane: row m=ln15(+tile), cols n=quad*4+reg
#pragma unroll
            for (int mt = 0; mt < 4; ++mt)
#pragma unroll
                for (int nt = 0; nt < 4; ++nt)
                    acc[mt][nt] = __builtin_amdgcn_mfma_f32_16x16x32_bf16(
                        bfr[nt], af[mt], acc[mt][nt], 0, 0, 0);
        }
        __syncthreads();             // all Xs A-frag reads for this layer done
#pragma unroll
        for (int mt = 0; mt < 4; ++mt) {
            int row = rbase + mt * 16 + ln15;
#pragma unroll
            for (int nt = 0; nt < 4; ++nt) {
                int col = cb + nt * 16 + quad * 4;
                ushort4 pv;
                pv.x = f2bf(fmaxf(acc[mt][nt][0] + bias[nt][0], 0.0f));
                pv.y = f2bf(fmaxf(acc[mt][nt][1] + bias[nt][1], 0.0f));
                pv.z = f2bf(fmaxf(acc[mt][nt][2] + bias[nt][2], 0.0f));
                pv.w = f2bf(fmaxf(acc[mt][nt][3] + bias[nt][3], 0.0f));
                *(ushort4*)&Xs[row * XS + col] = pv;   // 8 B vector write
            }
        }
        __syncthreads();             // activations visible to all waves
    }

    // ---------------- layer 4: [128 x 256] @ [256 x 16], wave wv owns rows wv*16..+15 ----------------
    {
        f32x4 acc4 = (f32x4){0.f, 0.f, 0.f, 0.f};
        const unsigned short* W4 = wsp + OFF4;
#pragma unroll
        for (int k0 = 0; k0 < 256; k0 += 32) {
            bf16x8 a = *(const bf16x8*)&Xs[(wv * 16 + ln15) * XS + k0 + quad * 8];
            bf16x8 bb = *(const bf16x8*)(W4 + ln15 * 256 + k0 + quad * 8);
            acc4 = __builtin_amdgcn_mfma_f32_16x16x32_bf16(a, bb, acc4, 0, 0, 0);
        }
        int plocal = wv * 4 + quad;          // point within block (0..31), reg r = branch e
        float a0 = areaS[plocal * 4 + 0];
        float a1 = areaS[plocal * 4 + 1];
        float a2 = areaS[plocal * 4 + 2];
        float a3 = areaS[plocal * 4 + 3];
        float tot = a0 + a1 + a2 + a3;
        float r = (acc4[0] * a3 + acc4[1] * a2 + acc4[2] * a1 + acc4[3] * a0) / tot;
        if (ln15 < 3) {
            size_t pg = (size_t)blockIdx.x * 32 + plocal;
            out[pg * 3 + ln15] = r + b4[ln15];
        }
    }
}

extern "C" void kernel_launch(void* const* d_in, const int* in_sizes, int n_in,
                              void* d_out, int out_size, void* d_ws, size_t ws_size,
                              hipStream_t stream) {
    const float* inp1  = (const float*)d_in[0];
    const float* inp2  = (const float*)d_in[1];
    const float* coord = (const float*)d_in[2];
    const float* cell  = (const float*)d_in[3];
    const float* w0 = (const float*)d_in[4];
    const float* b0 = (const float*)d_in[5];
    const float* w1 = (const float*)d_in[6];
    const float* b1 = (const float*)d_in[7];
    const float* w2 = (const float*)d_in[8];
    const float* b2 = (const float*)d_in[9];
    const float* w3 = (const float*)d_in[10];
    const float* b3 = (const float*)d_in[11];
    const float* w4 = (const float*)d_in[12];
    const float* b4 = (const float*)d_in[13];
    float* out = (float*)d_out;

    unsigned short* wsp = (unsigned short*)d_ws;
    unsigned short* t1 = wsp + WTOT;
    unsigned short* t2 = t1 + NHWC_ELEMS;

    prep_weights<<<(WTOT + 255) / 256, 256, 0, stream>>>(w0, w1, w2, w3, w4, wsp);
    transpose_nhwc<<<32768 / 256, 256, 0, stream>>>(inp1, inp2, t1, t2);
    liif_mlp<<<8192, 512, 0, stream>>>(t1, t2, coord, cell,
                                       b0, b1, b2, b3, b4, wsp, out);
}

// Round 6
// 653.839 us; speedup vs baseline: 1.2056x; 1.0313x over previous
//
#include <hip/hip_runtime.h>

#define XS 264           // X LDS row stride in bf16 elems (528 B; A b128 reads at bank floor)
#define CHUNK_ELEMS 8192 // one 32k x 256n weight chunk, layout [quad][n][8]

typedef __bf16 bf16x8 __attribute__((ext_vector_type(8)));
typedef float f32x4 __attribute__((ext_vector_type(4)));

__device__ __forceinline__ unsigned short f2bf(float f) {
    unsigned int u = __float_as_uint(f);
    u += 0x7fffu + ((u >> 16) & 1u);
    return (unsigned short)(u >> 16);
}

// Workspace layout (bf16 element offsets). Layers 0..3 stored as swizzled chunk
// images: chunk c covers k in [c*32,c*32+32); element (quad,n,j) at offset
// ((quad*256+n)*8+j) holds W[n][c*32+quad*8+j]. 16 consecutive lanes read
// 256 contiguous bytes -> fully coalesced global B-frag loads.
#define OFF0 0        // L0: 5 chunks (K padded 132->160, cols permuted [f1|f2|rel,cell|0])
#define OFF1 40960    // L1: 8 chunks
#define OFF2 106496   // L2
#define OFF3 172032   // L3
#define OFF4 237568   // w4p: 16 x 256 plain (rows 3..15 zero)
#define WTOT 241664
#define NHWC_ELEMS (4 * 4096 * 64)

__global__ void prep_weights(const float* __restrict__ w0, const float* __restrict__ w1,
                             const float* __restrict__ w2, const float* __restrict__ w3,
                             const float* __restrict__ w4, unsigned short* __restrict__ wsp) {
    int idx = blockIdx.x * 256 + threadIdx.x;
    if (idx >= WTOT) return;
    unsigned short v = 0;
    if (idx < OFF4) {
        int l, base;
        if (idx < OFF1)      { l = 0; base = OFF0; }
        else if (idx < OFF2) { l = 1; base = OFF1; }
        else if (idx < OFF3) { l = 2; base = OFF2; }
        else                 { l = 3; base = OFF3; }
        int j = idx - base;
        int c = j >> 13;
        int u = j & 8191;
        int flat16 = u >> 3, jj = u & 7;
        int quad = flat16 >> 8, n = flat16 & 255;
        int k = c * 32 + quad * 8 + jj;
        if (l == 0) {
            if (k < 64)       v = f2bf(w0[n * 132 + k]);
            else if (k < 128) v = f2bf(w0[n * 132 + 68 + (k - 64)]);
            else if (k < 132) v = f2bf(w0[n * 132 + 64 + (k - 128)]);
        } else {
            const float* w = (l == 1) ? w1 : (l == 2) ? w2 : w3;
            v = f2bf(w[n * 256 + k]);
        }
    } else {
        int j = idx - OFF4;
        if ((j >> 8) < 3) v = f2bf(w4[j]);
    }
    wsp[idx] = v;
}

__global__ void transpose_nhwc(const float* __restrict__ inp1, const float* __restrict__ inp2,
                               unsigned short* __restrict__ t1, unsigned short* __restrict__ t2) {
    int idx = blockIdx.x * 256 + threadIdx.x;
    int tensor = idx >> 14;
    int pos = idx & 16383;
    const float* src = tensor ? inp2 : inp1;
    unsigned short* dst = tensor ? t2 : t1;
    int b = pos >> 12, flat = pos & 4095;
    const float* s = src + (size_t)b * 64 * 4096 + flat;
    unsigned short* d = dst + (size_t)pos * 64;
#pragma unroll
    for (int c = 0; c < 64; ++c) d[c] = f2bf(s[c * 4096]);
}

__global__ __launch_bounds__(512, 2)
void liif_mlp(const unsigned short* __restrict__ t1, const unsigned short* __restrict__ t2,
              const float* __restrict__ coord, const float* __restrict__ cell,
              const float* __restrict__ b0, const float* __restrict__ b1,
              const float* __restrict__ b2, const float* __restrict__ b3,
              const float* __restrict__ b4,
              const unsigned short* __restrict__ wsp,
              float* __restrict__ out) {
    __shared__ unsigned short Xs[128 * XS];          // 67,584 B — activations only
    __shared__ float areaS[128];

    const int t = threadIdx.x;
    const int lane = t & 63;
    const int wv = t >> 6;            // 0..7

    // ---------------- gather: X [128 rows x 160 cols], 4 threads per row ----------------
    {
        int lr = t >> 2, sub = t & 3;
        int rg = blockIdx.x * 128 + lr;
        int p = rg >> 2, e = rg & 3;
        int b = p >> 16;
        float c0r = coord[(size_t)p * 2 + 0];
        float c1r = coord[(size_t)p * 2 + 1];
        float vx = (e & 2) ? 1.0f : -1.0f;
        float vy = (e & 1) ? 1.0f : -1.0f;
        const float lo = -1.0f + 1e-6f, hi = 1.0f - 1e-6f;
        float c0 = fminf(fmaxf(c0r + vx * (1.0f / 64.0f) + 1e-6f, lo), hi);
        float c1 = fminf(fmaxf(c1r + vy * (1.0f / 64.0f) + 1e-6f, lo), hi);
        int ih = (int)rintf((c0 + 1.0f) * 32.0f - 0.5f);
        ih = min(63, max(0, ih));
        int iw = (int)rintf((c1 + 1.0f) * 32.0f - 0.5f);
        iw = min(63, max(0, iw));
        int flat = ih * 64 + iw;
        size_t pos = (size_t)b * 4096 + flat;
        const uint4* g1 = (const uint4*)(t1 + pos * 64 + sub * 16);
        const uint4* g2 = (const uint4*)(t2 + pos * 64 + sub * 16);
        uint4 a0 = g1[0], a1 = g1[1];
        uint4 c0v = g2[0], c1v = g2[1];
        uint4* d1 = (uint4*)&Xs[lr * XS + sub * 16];
        uint4* d2 = (uint4*)&Xs[lr * XS + 64 + sub * 16];
        d1[0] = a0; d1[1] = a1;
        d2[0] = c0v; d2[1] = c1v;
        if (sub == 0) {
            float qc0 = -1.0f + (2.0f * ih + 1.0f) * (1.0f / 64.0f);
            float qc1 = -1.0f + (2.0f * iw + 1.0f) * (1.0f / 64.0f);
            float rel0 = (c0r - qc0) * 64.0f;
            float rel1 = (c1r - qc1) * 64.0f;
            Xs[lr * XS + 128] = f2bf(rel0);
            Xs[lr * XS + 129] = f2bf(rel1);
            Xs[lr * XS + 130] = f2bf(cell[(size_t)p * 2 + 0] * 64.0f);
            Xs[lr * XS + 131] = f2bf(cell[(size_t)p * 2 + 1] * 64.0f);
#pragma unroll
            for (int c = 132; c < 160; ++c) Xs[lr * XS + c] = 0;
            areaS[lr] = fabsf(rel0 * rel1) + 1e-9f;
        }
    }
    __syncthreads();

    const int ln15 = lane & 15;
    const int quad = lane >> 4;
    const int mw = wv >> 2;          // row half: rows mw*64 .. +63
    const int nw = wv & 3;           // col group: cols nw*64 .. +63
    const int cb = nw * 64;
    const int rbase = mw * 64;

    const unsigned short* wlbase[4] = {wsp + OFF0, wsp + OFF1, wsp + OFF2, wsp + OFF3};
    const float* bptr[4] = {b0, b1, b2, b3};

#pragma unroll
    for (int l = 0; l < 4; ++l) {
        const int nk = (l == 0) ? 5 : 8;
        f32x4 acc[4][4];
#pragma unroll
        for (int mt = 0; mt < 4; ++mt)
#pragma unroll
            for (int nt = 0; nt < 4; ++nt)
                acc[mt][nt] = (f32x4){0.f, 0.f, 0.f, 0.f};

        // bias: lane covers cols cb + nt*16 + quad*4 .. +3
        f32x4 bias[4];
#pragma unroll
        for (int nt = 0; nt < 4; ++nt)
            bias[nt] = *(const f32x4*)(bptr[l] + cb + nt * 16 + quad * 4);

        // per-lane weight base inside a chunk (coalesced: 16 lanes -> 256 B)
        const unsigned short* bp = wlbase[l] + ((size_t)quad * 256 + cb + ln15) * 8;

#pragma unroll
        for (int i = 0; i < nk; ++i) {
            bf16x8 bfr[4], af[4];
#pragma unroll
            for (int nt = 0; nt < 4; ++nt)
                bfr[nt] = *(const bf16x8*)(bp + (size_t)i * CHUNK_ELEMS + nt * 128);
#pragma unroll
            for (int mt = 0; mt < 4; ++mt)
                af[mt] = *(const bf16x8*)&Xs[(rbase + mt * 16 + ln15) * XS + i * 32 + quad * 8];
            // swapped operands: D = W·X^T -> lane: "col"(=ln15)=x_row, "row"(=quad*4+reg)=w_n
#pragma unroll
            for (int mt = 0; mt < 4; ++mt)
#pragma unroll
                for (int nt = 0; nt < 4; ++nt)
                    acc[mt][nt] = __builtin_amdgcn_mfma_f32_16x16x32_bf16(
                        bfr[nt], af[mt], acc[mt][nt], 0, 0, 0);
        }
        __syncthreads();             // all Xs k-input reads for this layer done
#pragma unroll
        for (int mt = 0; mt < 4; ++mt) {
            int row = rbase + mt * 16 + ln15;
#pragma unroll
            for (int nt = 0; nt < 4; ++nt) {
                int col = cb + nt * 16 + quad * 4;
                ushort4 pv;
                pv.x = f2bf(fmaxf(acc[mt][nt][0] + bias[nt][0], 0.0f));
                pv.y = f2bf(fmaxf(acc[mt][nt][1] + bias[nt][1], 0.0f));
                pv.z = f2bf(fmaxf(acc[mt][nt][2] + bias[nt][2], 0.0f));
                pv.w = f2bf(fmaxf(acc[mt][nt][3] + bias[nt][3], 0.0f));
                *(ushort4*)&Xs[row * XS + col] = pv;   // 8 B vector write
            }
        }
        __syncthreads();             // activations visible to all waves
    }

    // ---------------- layer 4: [128 x 256] @ [256 x 16], wave wv owns rows wv*16..+15 ----------------
    {
        f32x4 acc4 = (f32x4){0.f, 0.f, 0.f, 0.f};
        const unsigned short* W4 = wsp + OFF4;
#pragma unroll
        for (int k0 = 0; k0 < 256; k0 += 32) {
            bf16x8 a = *(const bf16x8*)&Xs[(wv * 16 + ln15) * XS + k0 + quad * 8];
            bf16x8 bb = *(const bf16x8*)(W4 + ln15 * 256 + k0 + quad * 8);
            acc4 = __builtin_amdgcn_mfma_f32_16x16x32_bf16(a, bb, acc4, 0, 0, 0);
        }
        int plocal = wv * 4 + quad;          // point within block (0..31), reg r = branch e
        float a0 = areaS[plocal * 4 + 0];
        float a1 = areaS[plocal * 4 + 1];
        float a2 = areaS[plocal * 4 + 2];
        float a3 = areaS[plocal * 4 + 3];
        float tot = a0 + a1 + a2 + a3;
        float r = (acc4[0] * a3 + acc4[1] * a2 + acc4[2] * a1 + acc4[3] * a0) / tot;
        if (ln15 < 3) {
            size_t pg = (size_t)blockIdx.x * 32 + plocal;
            out[pg * 3 + ln15] = r + b4[ln15];
        }
    }
}

extern "C" void kernel_launch(void* const* d_in, const int* in_sizes, int n_in,
                              void* d_out, int out_size, void* d_ws, size_t ws_size,
                              hipStream_t stream) {
    const float* inp1  = (const float*)d_in[0];
    const float* inp2  = (const float*)d_in[1];
    const float* coord = (const float*)d_in[2];
    const float* cell  = (const float*)d_in[3];
    const float* w0 = (const float*)d_in[4];
    const float* b0 = (const float*)d_in[5];
    const float* w1 = (const float*)d_in[6];
    const float* b1 = (const float*)d_in[7];
    const float* w2 = (const float*)d_in[8];
    const float* b2 = (const float*)d_in[9];
    const float* w3 = (const float*)d_in[10];
    const float* b3 = (const float*)d_in[11];
    const float* w4 = (const float*)d_in[12];
    const float* b4 = (const float*)d_in[13];
    float* out = (float*)d_out;

    unsigned short* wsp = (unsigned short*)d_ws;
    unsigned short* t1 = wsp + WTOT;
    unsigned short* t2 = t1 + NHWC_ELEMS;

    prep_weights<<<(WTOT + 255) / 256, 256, 0, stream>>>(w0, w1, w2, w3, w4, wsp);
    transpose_nhwc<<<32768 / 256, 256, 0, stream>>>(inp1, inp2, t1, t2);
    liif_mlp<<<8192, 512, 0, stream>>>(t1, t2, coord, cell,
                                       b0, b1, b2, b3, b4, wsp, out);
}

// Round 7
// 562.662 us; speedup vs baseline: 1.4010x; 1.1620x over previous
//
#include <hip/hip_runtime.h>

#define XS 264           // X LDS row stride in bf16 elems (528 B; A b128 reads at 2-way floor)
#define CHUNK_ELEMS 8192 // one 32k x 256n weight chunk, layout [quad][n][8]

typedef __bf16 bf16x8 __attribute__((ext_vector_type(8)));
typedef float f32x4 __attribute__((ext_vector_type(4)));

__device__ __forceinline__ unsigned short f2bf(float f) {
    unsigned int u = __float_as_uint(f);
    u += 0x7fffu + ((u >> 16) & 1u);
    return (unsigned short)(u >> 16);
}

// Workspace layout (bf16 element offsets). Layers 0..3 stored as swizzled chunk
// images: chunk c covers k in [c*32,c*32+32); element (quad,n,j) at offset
// ((quad*256+n)*8+j) holds W[n][c*32+quad*8+j]. 16 consecutive lanes read
// 256 contiguous bytes -> fully coalesced global B-frag loads.
#define OFF0 0        // L0: 5 chunks (K padded 132->160, cols permuted [f1|f2|rel,cell|0])
#define OFF1 40960    // L1: 8 chunks
#define OFF2 106496   // L2
#define OFF3 172032   // L3
#define OFF4 237568   // w4p: 16 x 256 plain (rows 3..15 zero)
#define WTOT 241664
#define NHWC_ELEMS (4 * 4096 * 64)

__global__ void prep_weights(const float* __restrict__ w0, const float* __restrict__ w1,
                             const float* __restrict__ w2, const float* __restrict__ w3,
                             const float* __restrict__ w4, unsigned short* __restrict__ wsp) {
    int idx = blockIdx.x * 256 + threadIdx.x;
    if (idx >= WTOT) return;
    unsigned short v = 0;
    if (idx < OFF4) {
        int l, base;
        if (idx < OFF1)      { l = 0; base = OFF0; }
        else if (idx < OFF2) { l = 1; base = OFF1; }
        else if (idx < OFF3) { l = 2; base = OFF2; }
        else                 { l = 3; base = OFF3; }
        int j = idx - base;
        int c = j >> 13;
        int u = j & 8191;
        int flat16 = u >> 3, jj = u & 7;
        int quad = flat16 >> 8, n = flat16 & 255;
        int k = c * 32 + quad * 8 + jj;
        if (l == 0) {
            if (k < 64)       v = f2bf(w0[n * 132 + k]);
            else if (k < 128) v = f2bf(w0[n * 132 + 68 + (k - 64)]);
            else if (k < 132) v = f2bf(w0[n * 132 + 64 + (k - 128)]);
        } else {
            const float* w = (l == 1) ? w1 : (l == 2) ? w2 : w3;
            v = f2bf(w[n * 256 + k]);
        }
    } else {
        int j = idx - OFF4;
        if ((j >> 8) < 3) v = f2bf(w4[j]);
    }
    wsp[idx] = v;
}

__global__ void transpose_nhwc(const float* __restrict__ inp1, const float* __restrict__ inp2,
                               unsigned short* __restrict__ t1, unsigned short* __restrict__ t2) {
    int idx = blockIdx.x * 256 + threadIdx.x;
    int tensor = idx >> 14;
    int pos = idx & 16383;
    const float* src = tensor ? inp2 : inp1;
    unsigned short* dst = tensor ? t2 : t1;
    int b = pos >> 12, flat = pos & 4095;
    const float* s = src + (size_t)b * 64 * 4096 + flat;
    unsigned short* d = dst + (size_t)pos * 64;
#pragma unroll
    for (int c = 0; c < 64; ++c) d[c] = f2bf(s[c * 4096]);
}

__global__ __launch_bounds__(512, 4)
void liif_mlp(const unsigned short* __restrict__ t1, const unsigned short* __restrict__ t2,
              const float* __restrict__ coord, const float* __restrict__ cell,
              const float* __restrict__ b0, const float* __restrict__ b1,
              const float* __restrict__ b2, const float* __restrict__ b3,
              const float* __restrict__ b4,
              const unsigned short* __restrict__ wsp,
              float* __restrict__ out) {
    __shared__ unsigned short Xs[128 * XS];          // 67,584 B — activations only
    __shared__ float areaS[128];

    const int t = threadIdx.x;
    const int lane = t & 63;
    const int wv = t >> 6;            // 0..7

    // ---------------- gather: X [128 rows x 160 cols], 4 threads per row ----------------
    {
        int lr = t >> 2, sub = t & 3;
        int rg = blockIdx.x * 128 + lr;
        int p = rg >> 2, e = rg & 3;
        int b = p >> 16;
        float c0r = coord[(size_t)p * 2 + 0];
        float c1r = coord[(size_t)p * 2 + 1];
        float vx = (e & 2) ? 1.0f : -1.0f;
        float vy = (e & 1) ? 1.0f : -1.0f;
        const float lo = -1.0f + 1e-6f, hi = 1.0f - 1e-6f;
        float c0 = fminf(fmaxf(c0r + vx * (1.0f / 64.0f) + 1e-6f, lo), hi);
        float c1 = fminf(fmaxf(c1r + vy * (1.0f / 64.0f) + 1e-6f, lo), hi);
        int ih = (int)rintf((c0 + 1.0f) * 32.0f - 0.5f);
        ih = min(63, max(0, ih));
        int iw = (int)rintf((c1 + 1.0f) * 32.0f - 0.5f);
        iw = min(63, max(0, iw));
        int flat = ih * 64 + iw;
        size_t pos = (size_t)b * 4096 + flat;
        const uint4* g1 = (const uint4*)(t1 + pos * 64 + sub * 16);
        const uint4* g2 = (const uint4*)(t2 + pos * 64 + sub * 16);
        uint4 a0 = g1[0], a1 = g1[1];
        uint4 c0v = g2[0], c1v = g2[1];
        uint4* d1 = (uint4*)&Xs[lr * XS + sub * 16];
        uint4* d2 = (uint4*)&Xs[lr * XS + 64 + sub * 16];
        d1[0] = a0; d1[1] = a1;
        d2[0] = c0v; d2[1] = c1v;
        if (sub == 0) {
            float qc0 = -1.0f + (2.0f * ih + 1.0f) * (1.0f / 64.0f);
            float qc1 = -1.0f + (2.0f * iw + 1.0f) * (1.0f / 64.0f);
            float rel0 = (c0r - qc0) * 64.0f;
            float rel1 = (c1r - qc1) * 64.0f;
            Xs[lr * XS + 128] = f2bf(rel0);
            Xs[lr * XS + 129] = f2bf(rel1);
            Xs[lr * XS + 130] = f2bf(cell[(size_t)p * 2 + 0] * 64.0f);
            Xs[lr * XS + 131] = f2bf(cell[(size_t)p * 2 + 1] * 64.0f);
#pragma unroll
            for (int c = 132; c < 160; ++c) Xs[lr * XS + c] = 0;
            areaS[lr] = fabsf(rel0 * rel1) + 1e-9f;
        }
    }
    __syncthreads();

    const int ln15 = lane & 15;
    const int quad = lane >> 4;
    const int mw = wv >> 2;          // row half: rows mw*64 .. +63
    const int nw = wv & 3;           // col group: cols nw*64 .. +63
    const int cb = nw * 64;
    const int rbase = mw * 64;

    const unsigned short* wlbase[4] = {wsp + OFF0, wsp + OFF1, wsp + OFF2, wsp + OFF3};
    const float* bptr[4] = {b0, b1, b2, b3};

#pragma unroll
    for (int l = 0; l < 4; ++l) {
        const int nk = (l == 0) ? 5 : 8;
        f32x4 acc[4][4];
#pragma unroll
        for (int mt = 0; mt < 4; ++mt)
#pragma unroll
            for (int nt = 0; nt < 4; ++nt)
                acc[mt][nt] = (f32x4){0.f, 0.f, 0.f, 0.f};

        // per-lane weight base inside a chunk (coalesced: 16 lanes -> 256 B)
        const unsigned short* bp = wlbase[l] + ((size_t)quad * 256 + cb + ln15) * 8;

#pragma unroll
        for (int i = 0; i < nk; ++i) {
            bf16x8 bfr[4], af[4];
#pragma unroll
            for (int nt = 0; nt < 4; ++nt)
                bfr[nt] = *(const bf16x8*)(bp + (size_t)i * CHUNK_ELEMS + nt * 128);
#pragma unroll
            for (int mt = 0; mt < 4; ++mt)
                af[mt] = *(const bf16x8*)&Xs[(rbase + mt * 16 + ln15) * XS + i * 32 + quad * 8];
            // swapped operands: D = W·X^T -> lane: "col"(=ln15)=x_row, "row"(=quad*4+reg)=w_n
#pragma unroll
            for (int mt = 0; mt < 4; ++mt)
#pragma unroll
                for (int nt = 0; nt < 4; ++nt)
                    acc[mt][nt] = __builtin_amdgcn_mfma_f32_16x16x32_bf16(
                        bfr[nt], af[mt], acc[mt][nt], 0, 0, 0);
        }
        __syncthreads();             // all Xs k-input reads for this layer done

        // bias loaded here (off the k-loop critical path; keeps in-loop VGPRs low)
        const float* bl = bptr[l];
#pragma unroll
        for (int mt = 0; mt < 4; ++mt) {
            int row = rbase + mt * 16 + ln15;
#pragma unroll
            for (int nt = 0; nt < 4; ++nt) {
                f32x4 bv = *(const f32x4*)(bl + cb + nt * 16 + quad * 4);
                int col = cb + nt * 16 + quad * 4;
                ushort4 pv;
                pv.x = f2bf(fmaxf(acc[mt][nt][0] + bv[0], 0.0f));
                pv.y = f2bf(fmaxf(acc[mt][nt][1] + bv[1], 0.0f));
                pv.z = f2bf(fmaxf(acc[mt][nt][2] + bv[2], 0.0f));
                pv.w = f2bf(fmaxf(acc[mt][nt][3] + bv[3], 0.0f));
                *(ushort4*)&Xs[row * XS + col] = pv;   // 8 B vector write
            }
        }
        __syncthreads();             // activations visible to all waves
    }

    // ---------------- layer 4: [128 x 256] @ [256 x 16], wave wv owns rows wv*16..+15 ----------------
    {
        f32x4 acc4 = (f32x4){0.f, 0.f, 0.f, 0.f};
        const unsigned short* W4 = wsp + OFF4;
#pragma unroll
        for (int k0 = 0; k0 < 256; k0 += 32) {
            bf16x8 a = *(const bf16x8*)&Xs[(wv * 16 + ln15) * XS + k0 + quad * 8];
            bf16x8 bb = *(const bf16x8*)(W4 + ln15 * 256 + k0 + quad * 8);
            acc4 = __builtin_amdgcn_mfma_f32_16x16x32_bf16(a, bb, acc4, 0, 0, 0);
        }
        int plocal = wv * 4 + quad;          // point within block (0..31), reg r = branch e
        float a0 = areaS[plocal * 4 + 0];
        float a1 = areaS[plocal * 4 + 1];
        float a2 = areaS[plocal * 4 + 2];
        float a3 = areaS[plocal * 4 + 3];
        float tot = a0 + a1 + a2 + a3;
        float r = (acc4[0] * a3 + acc4[1] * a2 + acc4[2] * a1 + acc4[3] * a0) / tot;
        if (ln15 < 3) {
            size_t pg = (size_t)blockIdx.x * 32 + plocal;
            out[pg * 3 + ln15] = r + b4[ln15];
        }
    }
}

extern "C" void kernel_launch(void* const* d_in, const int* in_sizes, int n_in,
                              void* d_out, int out_size, void* d_ws, size_t ws_size,
                              hipStream_t stream) {
    const float* inp1  = (const float*)d_in[0];
    const float* inp2  = (const float*)d_in[1];
    const float* coord = (const float*)d_in[2];
    const float* cell  = (const float*)d_in[3];
    const float* w0 = (const float*)d_in[4];
    const float* b0 = (const float*)d_in[5];
    const float* w1 = (const float*)d_in[6];
    const float* b1 = (const float*)d_in[7];
    const float* w2 = (const float*)d_in[8];
    const float* b2 = (const float*)d_in[9];
    const float* w3 = (const float*)d_in[10];
    const float* b3 = (const float*)d_in[11];
    const float* w4 = (const float*)d_in[12];
    const float* b4 = (const float*)d_in[13];
    float* out = (float*)d_out;

    unsigned short* wsp = (unsigned short*)d_ws;
    unsigned short* t1 = wsp + WTOT;
    unsigned short* t2 = t1 + NHWC_ELEMS;

    prep_weights<<<(WTOT + 255) / 256, 256, 0, stream>>>(w0, w1, w2, w3, w4, wsp);
    transpose_nhwc<<<32768 / 256, 256, 0, stream>>>(inp1, inp2, t1, t2);
    liif_mlp<<<8192, 512, 0, stream>>>(t1, t2, coord, cell,
                                       b0, b1, b2, b3, b4, wsp, out);
}